// Round 4
// baseline (356.303 us; speedup 1.0000x reference)
//
#include <hip/hip_runtime.h>
#include <hip/hip_fp16.h>
#include <hip/hip_cooperative_groups.h>

namespace cg = cooperative_groups;

#define N_NODES 50000
#define N_EDGES 800000
#define IN_DIM  64
#define OUT_DIM 32
#define NODES_PER_BIN 32
#define NBINS   1563                 // ceil(50000/32)
#define NCLS    8
#define CLS_CAP 128                  // per (bin,class): mean 64, +8 sigma; chaining backstops
#define BIN_SLOTS (NCLS * CLS_CAP)   // 1024
#define NCURS   (NBINS * NCLS)       // 12504
#define CUR_STRIDE 16                // one cursor per 64B line (R20)
#define FC_NODES_PER_BLOCK 16
#define FC_BLOCKS (N_NODES / FC_NODES_PER_BLOCK)  // 3125
#define ACC_VBS (NBINS * 2)          // 3126 accum virtual blocks

// physical XCD id (gfx950: HW_REG_XCC_ID = hwreg 20; learn_hip m09)
__device__ __forceinline__ int get_xcc_id() {
  return (int)(__builtin_amdgcn_s_getreg(63508) & 7u);  // 20 | (31<<11)
}

// R21: ONE cooperative kernel replaces {memset, fused_fc_scatter, accum}.
// Rationale: R1-R3 showed total = K1 + ~107us CONSTANT, with every K2
// dispatch provably <54us (top-5 table saturated by K1 instances) -> large
// fixed inter-dispatch cost.  Merging deletes 2 dispatch boundaries; kernel
// work is byte-identical to R20, so the dur_us delta measures that cost.
// Phases: P0 zero cursors | P1 scatter(grid-stride)+fc(vb-stride) |
// grid.sync (device-scope fence: ezh2/a_tab/payload/cursor visible) |
// P2 accum(vb-stride).  LDS: one 16KB arena overlaid (fc: Wl 8K + hs4 8K;
// accum: rec 4K + sorted 4K + counters).  __launch_bounds__(256,8) caps
// VGPR at 64 -> 8 blocks/CU guaranteed resident -> grid 2048 always legal
// for cooperative launch (occupancy query double-checks at runtime).
__global__ __launch_bounds__(256, 8) void gat_mega(
    const float* __restrict__ h, const float* __restrict__ Wfc,
    const float* __restrict__ bfc, const float* __restrict__ Watt,
    const float* __restrict__ batt,
    const int* __restrict__ src, const int* __restrict__ dst,
    const float* __restrict__ weight,
    __half2* __restrict__ ezh2, float4* __restrict__ a_tab,
    int* __restrict__ cursor, unsigned int* __restrict__ payload,
    float* __restrict__ out) {
  cg::grid_group grid = cg::this_grid();
  __shared__ __align__(16) unsigned char smem[16384];
  int t = threadIdx.x;
  const int gsz = (int)gridDim.x;

  // ---- P0: zero cursors (replaces hipMemsetAsync dispatch) ----
  for (int i = blockIdx.x * 256 + t; i < NCURS * CUR_STRIDE; i += gsz * 256)
    cursor[i] = 0;
  grid.sync();

  // ---- P1a: scatter, 1 edge/thread grid-stride ----
  {
    int xcc = get_xcc_id();                  // wave-uniform
    for (int e = blockIdx.x * 256 + t; e < N_EDGES; e += gsz * 256) {
      int s = src[e], d = dst[e];
      float wv = weight[e];
      unsigned int r = ((unsigned int)s << 16) | ((unsigned int)(d & 31) << 11) |
                       ((unsigned int)__float2int_rn(wv * 2047.0f) & 2047u);
      int bin = d >> 5;
      int c = xcc;
#pragma unroll 1
      for (int a = 0; a < NCLS; ++a) {       // first atomic ~always wins
        int pos = atomicAdd(&cursor[(c * NBINS + bin) * CUR_STRIDE], 1);
        if (pos < CLS_CAP) {
          payload[(size_t)bin * BIN_SLOTS + c * CLS_CAP + pos] = r;
          break;
        }
        c = (c + 1) & 7;
      }
    }
  }

  // ---- P1b: fc, vb-stride (W loaded to LDS once, reused across vbs) ----
  {
    float* Wl = (float*)smem;                          // 8 KB
    float4* hs4 = (float4*)(smem + 8192);              // 8 KB
    int w = t >> 6, lane = t & 63, o = lane & 31, b = lane >> 5;
    __syncthreads();                                   // arena handoff
    for (int i = t; i < 512; i += 256)
      ((float4*)Wl)[i] = ((const float4*)Wfc)[i];
    float bo = bfc[o];
    float wo1 = Watt[o], wo2 = Watt[OUT_DIM + o];
    for (int vb = blockIdx.x; vb < FC_BLOCKS; vb += gsz) {
      __syncthreads();     // prev vb's hs4 reads done (also covers Wl ready)
      int n0 = vb * FC_NODES_PER_BLOCK;
#pragma unroll
      for (int f = t; f < FC_NODES_PER_BLOCK * 2 * 16; f += 256) {
        int ns = f >> 5, sb = (f >> 4) & 1, i4 = f & 15;
        hs4[f] = ((const float4*)h)[((size_t)sb * N_NODES + (n0 + ns)) * 16 + i4];
      }
      __syncthreads();
#pragma unroll
      for (int k = 0; k < 4; ++k) {
        int ns = w * 4 + k;
        int n = n0 + ns;
        float acc = bo;
#pragma unroll
        for (int i4 = 0; i4 < 16; ++i4) {
          float4 hv = hs4[(ns * 2 + b) * 16 + i4];   // wave-broadcast
          acc = fmaf(hv.x, Wl[(i4 * 4 + 0) * OUT_DIM + o], acc);
          acc = fmaf(hv.y, Wl[(i4 * 4 + 1) * OUT_DIM + o], acc);
          acc = fmaf(hv.z, Wl[(i4 * 4 + 2) * OUT_DIM + o], acc);
          acc = fmaf(hv.w, Wl[(i4 * 4 + 3) * OUT_DIM + o], acc);
        }
        float ez = __expf(acc);
        float ezo = __shfl(ez, lane ^ 32, 64);       // partner batch's value
        if (b == 0) {
          __half2 hv2;
          hv2.x = __float2half(ez);
          hv2.y = __float2half(ezo);
          ezh2[(size_t)n * OUT_DIM + o] = hv2;
        }
        float ps = acc * wo1, pd = acc * wo2;
#pragma unroll
        for (int m = 16; m >= 1; m >>= 1) {
          ps += __shfl_xor(ps, m, 64);
          pd += __shfl_xor(pd, m, 64);
        }
        if (o == 0) ((float2*)(a_tab + n))[b] = make_float2(ps, pd);
      }
    }
  }

  grid.sync();   // device-scope fence: P1 writes visible to all XCDs

  // ---- P2: accum, vb-stride ----
  {
    unsigned int* rec    = (unsigned int*)smem;          // 4 KB
    unsigned int* sorted = rec + BIN_SLOTS;              // 4 KB
    int* c8   = (int*)(sorted + BIN_SLOTS);
    int* hist = c8 + NCLS;
    int* off  = hist + NODES_PER_BIN;
    int* cnt2 = off + NODES_PER_BIN;
    const float4* a_tab4 = a_tab;
    int w = t >> 6, lane = t & 63, o = lane & 31, rr = lane >> 5;
    float wA = Watt[2 * OUT_DIM];
    float bA = batt[0];
    const float kInvQ = 1.0f / 2047.0f;
    for (int vb = blockIdx.x; vb < ACC_VBS; vb += gsz) {
      __syncthreads();                       // LDS reuse guard across vbs/phases
      int bin = vb >> 1;
      int half = vb & 1;
      if (t < NCLS) {
        int c = cursor[(t * NBINS + bin) * CUR_STRIDE];
        c8[t] = c > CLS_CAP ? CLS_CAP : (c < 0 ? 0 : c);
      }
      if (t < NODES_PER_BIN) { hist[t] = 0; cnt2[t] = 0; }
      __syncthreads();
      const unsigned int* seg = payload + (size_t)bin * BIN_SLOTS;
      for (int j = t; j < BIN_SLOTS; j += 256) {
        if ((j & (CLS_CAP - 1)) < c8[j >> 7]) {   // only fetch filled slots
          unsigned int r = seg[j];
          rec[j] = r;
          atomicAdd(&hist[(r >> 11) & 31], 1);
        }
      }
      __syncthreads();
      if (t < 64) {  // exclusive shuffle scan of 32 counts (wave 0)
        int v = (t < 32) ? hist[t] : 0;
        int orig = v;
#pragma unroll
        for (int d1 = 1; d1 < 32; d1 <<= 1) {
          int x = __shfl_up(v, d1, 64);
          if (t >= d1) v += x;
        }
        if (t < 32) off[t] = v - orig;
      }
      __syncthreads();
      for (int j = t; j < BIN_SLOTS; j += 256) {
        if ((j & (CLS_CAP - 1)) < c8[j >> 7]) {
          unsigned int r = rec[j];
          int nl = (r >> 11) & 31;
          sorted[off[nl] + atomicAdd(&cnt2[nl], 1)] = r;  // total <=1024
        }
      }
      __syncthreads();

#pragma unroll
      for (int k = 0; k < 4; ++k) {
        int nl = half * 16 + w * 4 + k;             // wave-uniform
        int n = bin * NODES_PER_BIN + nl;
        if (n >= N_NODES) break;
        int cn = hist[nl];
        int base = off[nl];
        float4 an = a_tab4[n];
        float adx = an.y, ady = an.w;               // a_d(n,b0), a_d(n,b1)
        float2 num = make_float2(0.f, 0.f), den = make_float2(0.f, 0.f);
        int i = 0;
        for (; i + 3 < cn; i += 4) {                // 2 records/half-wave iter
          unsigned int rA = sorted[base + i + rr];
          unsigned int rB = sorted[base + i + 2 + rr];
          int sA = rA >> 16, sB = rB >> 16;
          __half2 eA2 = ezh2[(size_t)sA * OUT_DIM + o];
          __half2 eB2 = ezh2[(size_t)sB * OUT_DIM + o];
          float4 aA = a_tab4[sA];
          float4 aB = a_tab4[sB];
          float wtA = fmaf((rA & 2047u) * kInvQ, wA, bA);
          float wtB = fmaf((rB & 2047u) * kInvQ, wA, bA);
          float l0A = aA.x + adx + wtA, l1A = aA.z + ady + wtA;
          float l0B = aB.x + adx + wtB, l1B = aB.z + ady + wtB;
          l0A = l0A > 0.f ? l0A : 0.01f * l0A;
          l1A = l1A > 0.f ? l1A : 0.01f * l1A;
          l0B = l0B > 0.f ? l0B : 0.01f * l0B;
          l1B = l1B > 0.f ? l1B : 0.01f * l1B;
          float2 eA = __half22float2(eA2);
          float2 eB = __half22float2(eB2);
          num.x = fmaf(eA.x, l0A, num.x); num.y = fmaf(eA.y, l1A, num.y);
          den.x += eA.x;                  den.y += eA.y;
          num.x = fmaf(eB.x, l0B, num.x); num.y = fmaf(eB.y, l1B, num.y);
          den.x += eB.x;                  den.y += eB.y;
        }
        for (; i < cn; i += 2) {                    // guarded tail
          int idx = i + rr;
          float m = (idx < cn) ? 1.f : 0.f;
          int idxc = (idx < cn) ? idx : cn - 1;
          unsigned int r = sorted[base + idxc];
          int s = r >> 16;
          __half2 e2 = ezh2[(size_t)s * OUT_DIM + o];
          float4 as4 = a_tab4[s];
          float wt = fmaf((r & 2047u) * kInvQ, wA, bA);
          float l0 = as4.x + adx + wt, l1 = as4.z + ady + wt;
          l0 = l0 > 0.f ? l0 : 0.01f * l0;
          l1 = l1 > 0.f ? l1 : 0.01f * l1;
          float2 e = __half22float2(e2);
          e.x *= m; e.y *= m;
          num.x = fmaf(e.x, l0, num.x); num.y = fmaf(e.y, l1, num.y);
          den.x += e.x;                 den.y += e.y;
        }
        num.x += __shfl_xor(num.x, 32, 64);
        num.y += __shfl_xor(num.y, 32, 64);
        den.x += __shfl_xor(den.x, 32, 64);
        den.y += __shfl_xor(den.y, 32, 64);
        if (rr == 0) {
          float v0 = (cn > 0) ? num.x / den.x : 0.f;
          float v1 = (cn > 0) ? num.y / den.y : 0.f;
          out[((size_t)0 * N_NODES + n) * OUT_DIM + o] = v0;
          out[((size_t)1 * N_NODES + n) * OUT_DIM + o] = v1;
        }
      }
    }
  }
}

extern "C" void kernel_launch(void* const* d_in, const int* in_sizes, int n_in,
                              void* d_out, int out_size, void* d_ws, size_t ws_size,
                              hipStream_t stream) {
  const float* h      = (const float*)d_in[0];
  const float* weight = (const float*)d_in[1];
  const int*   src    = (const int*)d_in[2];
  const int*   dst    = (const int*)d_in[3];
  const float* Wfc    = (const float*)d_in[4];
  const float* bfc    = (const float*)d_in[5];
  const float* Watt   = (const float*)d_in[6];
  const float* batt   = (const float*)d_in[7];
  float* out = (float*)d_out;

  // workspace (~14.4 MB)
  float4*       a_tab   = (float4*)d_ws;                                  // 800 KB
  unsigned int* payload = (unsigned int*)(a_tab + N_NODES);               // 6.4 MB
  __half2*      ezh2    = (__half2*)(payload + (size_t)NBINS * BIN_SLOTS);// 6.4 MB
  int*          cursor  = (int*)(ezh2 + (size_t)N_NODES * OUT_DIM);       // 800 KB (padded)

  // Cooperative grid: min(occupancy capacity, 2048).  __launch_bounds__(256,8)
  // guarantees >=8 blocks/CU so 2048 is expected; query once and cache.
  static int grid_blocks = 0;
  if (grid_blocks == 0) {
    int mb = 0;
    if (hipOccupancyMaxActiveBlocksPerMultiprocessor(&mb, gat_mega, 256, 0)
            != hipSuccess || mb < 1)
      mb = 4;                                   // ultra-safe fallback
    grid_blocks = mb * 256;                     // 256 CUs on MI355X
    if (grid_blocks > 2048) grid_blocks = 2048;
  }

  void* args[] = {(void*)&h,    (void*)&Wfc,  (void*)&bfc,  (void*)&Watt,
                  (void*)&batt, (void*)&src,  (void*)&dst,  (void*)&weight,
                  (void*)&ezh2, (void*)&a_tab,(void*)&cursor,(void*)&payload,
                  (void*)&out};
  (void)hipLaunchCooperativeKernel(gat_mega, dim3(grid_blocks), dim3(256),
                                   args, 0, stream);
}

// Round 5
// 323.368 us; speedup vs baseline: 1.1018x; 1.1018x over previous
//
#include <hip/hip_runtime.h>
#include <hip/hip_fp16.h>
#include <hip/hip_cooperative_groups.h>

namespace cg = cooperative_groups;

#define N_NODES 50000
#define N_EDGES 800000
#define IN_DIM  64
#define OUT_DIM 32
#define NODES_PER_BIN 32
#define NBINS   1563                 // ceil(50000/32)
#define NCLS    8
#define CLS_CAP 128                  // per (bin,class): mean 64, +8 sigma; chaining backstops
#define BIN_SLOTS (NCLS * CLS_CAP)   // 1024
#define NCURS   (NBINS * NCLS)       // 12504
#define CUR_STRIDE 16                // one cursor per 64B line (R20)
#define FC_NODES_PER_BLOCK 16
#define FC_BLOCKS (N_NODES / FC_NODES_PER_BLOCK)  // 3125
#define ACC_VBS (NBINS * 2)          // 3126 accum virtual blocks

// physical XCD id (gfx950: HW_REG_XCC_ID = hwreg 20; learn_hip m09)
__device__ __forceinline__ int get_xcc_id() {
  return (int)(__builtin_amdgcn_s_getreg(63508) & 7u);  // 20 | (31<<11)
}

// R22: mega kernel (R21 structure) with the register budget FIXED.
// R21's __launch_bounds__(256,8) forced VGPR=32 -> fc/accum inner loops
// spilled to scratch (FETCH +41MB, WRITE +14MB, VALUBusy 8%, 371us).
// (256,4) restores the R18-measured 56-60 VGPR, zero-spill codegen.
// Phases: P0 zero cursors | P1 scatter(grid-stride)+fc(vb-stride),
// overlapped across the persistent block pool | grid.sync | P2 accum.
__global__ __launch_bounds__(256, 4) void gat_mega(
    const float* __restrict__ h, const float* __restrict__ Wfc,
    const float* __restrict__ bfc, const float* __restrict__ Watt,
    const float* __restrict__ batt,
    const int* __restrict__ src, const int* __restrict__ dst,
    const float* __restrict__ weight,
    __half2* __restrict__ ezh2, float4* __restrict__ a_tab,
    int* __restrict__ cursor, unsigned int* __restrict__ payload,
    float* __restrict__ out) {
  cg::grid_group grid = cg::this_grid();
  __shared__ __align__(16) unsigned char smem[16384];
  int t = threadIdx.x;
  const int gsz = (int)gridDim.x;

  // ---- P0: zero cursors (replaces hipMemsetAsync dispatch) ----
  for (int i = blockIdx.x * 256 + t; i < NCURS * CUR_STRIDE; i += gsz * 256)
    cursor[i] = 0;
  grid.sync();

  // ---- P1a: scatter, 1 edge/thread grid-stride ----
  {
    int xcc = get_xcc_id();                  // wave-uniform
    for (int e = blockIdx.x * 256 + t; e < N_EDGES; e += gsz * 256) {
      int s = src[e], d = dst[e];
      float wv = weight[e];
      unsigned int r = ((unsigned int)s << 16) | ((unsigned int)(d & 31) << 11) |
                       ((unsigned int)__float2int_rn(wv * 2047.0f) & 2047u);
      int bin = d >> 5;
      int c = xcc;
#pragma unroll 1
      for (int a = 0; a < NCLS; ++a) {       // first atomic ~always wins
        int pos = atomicAdd(&cursor[(c * NBINS + bin) * CUR_STRIDE], 1);
        if (pos < CLS_CAP) {
          payload[(size_t)bin * BIN_SLOTS + c * CLS_CAP + pos] = r;
          break;
        }
        c = (c + 1) & 7;
      }
    }
  }

  // ---- P1b: fc, vb-stride (W loaded to LDS once, reused across vbs) ----
  {
    float* Wl = (float*)smem;                          // 8 KB
    float4* hs4 = (float4*)(smem + 8192);              // 8 KB
    int w = t >> 6, lane = t & 63, o = lane & 31, b = lane >> 5;
    __syncthreads();                                   // arena handoff
    for (int i = t; i < 512; i += 256)
      ((float4*)Wl)[i] = ((const float4*)Wfc)[i];
    float bo = bfc[o];
    float wo1 = Watt[o], wo2 = Watt[OUT_DIM + o];
    for (int vb = blockIdx.x; vb < FC_BLOCKS; vb += gsz) {
      __syncthreads();     // prev vb's hs4 reads done (also covers Wl ready)
      int n0 = vb * FC_NODES_PER_BLOCK;
#pragma unroll
      for (int f = t; f < FC_NODES_PER_BLOCK * 2 * 16; f += 256) {
        int ns = f >> 5, sb = (f >> 4) & 1, i4 = f & 15;
        hs4[f] = ((const float4*)h)[((size_t)sb * N_NODES + (n0 + ns)) * 16 + i4];
      }
      __syncthreads();
#pragma unroll
      for (int k = 0; k < 4; ++k) {
        int ns = w * 4 + k;
        int n = n0 + ns;
        float acc = bo;
#pragma unroll
        for (int i4 = 0; i4 < 16; ++i4) {
          float4 hv = hs4[(ns * 2 + b) * 16 + i4];   // wave-broadcast
          acc = fmaf(hv.x, Wl[(i4 * 4 + 0) * OUT_DIM + o], acc);
          acc = fmaf(hv.y, Wl[(i4 * 4 + 1) * OUT_DIM + o], acc);
          acc = fmaf(hv.z, Wl[(i4 * 4 + 2) * OUT_DIM + o], acc);
          acc = fmaf(hv.w, Wl[(i4 * 4 + 3) * OUT_DIM + o], acc);
        }
        float ez = __expf(acc);
        float ezo = __shfl(ez, lane ^ 32, 64);       // partner batch's value
        if (b == 0) {
          __half2 hv2;
          hv2.x = __float2half(ez);
          hv2.y = __float2half(ezo);
          ezh2[(size_t)n * OUT_DIM + o] = hv2;
        }
        float ps = acc * wo1, pd = acc * wo2;
#pragma unroll
        for (int m = 16; m >= 1; m >>= 1) {
          ps += __shfl_xor(ps, m, 64);
          pd += __shfl_xor(pd, m, 64);
        }
        if (o == 0) ((float2*)(a_tab + n))[b] = make_float2(ps, pd);
      }
    }
  }

  grid.sync();   // device-scope fence: P1 writes visible to all XCDs

  // ---- P2: accum, vb-stride ----
  {
    unsigned int* rec    = (unsigned int*)smem;          // 4 KB
    unsigned int* sorted = rec + BIN_SLOTS;              // 4 KB
    int* c8   = (int*)(sorted + BIN_SLOTS);
    int* hist = c8 + NCLS;
    int* off  = hist + NODES_PER_BIN;
    int* cnt2 = off + NODES_PER_BIN;
    const float4* a_tab4 = a_tab;
    int w = t >> 6, lane = t & 63, o = lane & 31, rr = lane >> 5;
    float wA = Watt[2 * OUT_DIM];
    float bA = batt[0];
    const float kInvQ = 1.0f / 2047.0f;
    for (int vb = blockIdx.x; vb < ACC_VBS; vb += gsz) {
      __syncthreads();                       // LDS reuse guard across vbs/phases
      int bin = vb >> 1;
      int half = vb & 1;
      if (t < NCLS) {
        int c = cursor[(t * NBINS + bin) * CUR_STRIDE];
        c8[t] = c > CLS_CAP ? CLS_CAP : (c < 0 ? 0 : c);
      }
      if (t < NODES_PER_BIN) { hist[t] = 0; cnt2[t] = 0; }
      __syncthreads();
      const unsigned int* seg = payload + (size_t)bin * BIN_SLOTS;
      for (int j = t; j < BIN_SLOTS; j += 256) {
        if ((j & (CLS_CAP - 1)) < c8[j >> 7]) {   // only fetch filled slots
          unsigned int r = seg[j];
          rec[j] = r;
          atomicAdd(&hist[(r >> 11) & 31], 1);
        }
      }
      __syncthreads();
      if (t < 64) {  // exclusive shuffle scan of 32 counts (wave 0)
        int v = (t < 32) ? hist[t] : 0;
        int orig = v;
#pragma unroll
        for (int d1 = 1; d1 < 32; d1 <<= 1) {
          int x = __shfl_up(v, d1, 64);
          if (t >= d1) v += x;
        }
        if (t < 32) off[t] = v - orig;
      }
      __syncthreads();
      for (int j = t; j < BIN_SLOTS; j += 256) {
        if ((j & (CLS_CAP - 1)) < c8[j >> 7]) {
          unsigned int r = rec[j];
          int nl = (r >> 11) & 31;
          sorted[off[nl] + atomicAdd(&cnt2[nl], 1)] = r;  // total <=1024
        }
      }
      __syncthreads();

#pragma unroll
      for (int k = 0; k < 4; ++k) {
        int nl = half * 16 + w * 4 + k;             // wave-uniform
        int n = bin * NODES_PER_BIN + nl;
        if (n >= N_NODES) break;
        int cn = hist[nl];
        int base = off[nl];
        float4 an = a_tab4[n];
        float adx = an.y, ady = an.w;               // a_d(n,b0), a_d(n,b1)
        float2 num = make_float2(0.f, 0.f), den = make_float2(0.f, 0.f);
        int i = 0;
        for (; i + 3 < cn; i += 4) {                // 2 records/half-wave iter
          unsigned int rA = sorted[base + i + rr];
          unsigned int rB = sorted[base + i + 2 + rr];
          int sA = rA >> 16, sB = rB >> 16;
          __half2 eA2 = ezh2[(size_t)sA * OUT_DIM + o];
          __half2 eB2 = ezh2[(size_t)sB * OUT_DIM + o];
          float4 aA = a_tab4[sA];
          float4 aB = a_tab4[sB];
          float wtA = fmaf((rA & 2047u) * kInvQ, wA, bA);
          float wtB = fmaf((rB & 2047u) * kInvQ, wA, bA);
          float l0A = aA.x + adx + wtA, l1A = aA.z + ady + wtA;
          float l0B = aB.x + adx + wtB, l1B = aB.z + ady + wtB;
          l0A = l0A > 0.f ? l0A : 0.01f * l0A;
          l1A = l1A > 0.f ? l1A : 0.01f * l1A;
          l0B = l0B > 0.f ? l0B : 0.01f * l0B;
          l1B = l1B > 0.f ? l1B : 0.01f * l1B;
          float2 eA = __half22float2(eA2);
          float2 eB = __half22float2(eB2);
          num.x = fmaf(eA.x, l0A, num.x); num.y = fmaf(eA.y, l1A, num.y);
          den.x += eA.x;                  den.y += eA.y;
          num.x = fmaf(eB.x, l0B, num.x); num.y = fmaf(eB.y, l1B, num.y);
          den.x += eB.x;                  den.y += eB.y;
        }
        for (; i < cn; i += 2) {                    // guarded tail
          int idx = i + rr;
          float m = (idx < cn) ? 1.f : 0.f;
          int idxc = (idx < cn) ? idx : cn - 1;
          unsigned int r = sorted[base + idxc];
          int s = r >> 16;
          __half2 e2 = ezh2[(size_t)s * OUT_DIM + o];
          float4 as4 = a_tab4[s];
          float wt = fmaf((r & 2047u) * kInvQ, wA, bA);
          float l0 = as4.x + adx + wt, l1 = as4.z + ady + wt;
          l0 = l0 > 0.f ? l0 : 0.01f * l0;
          l1 = l1 > 0.f ? l1 : 0.01f * l1;
          float2 e = __half22float2(e2);
          e.x *= m; e.y *= m;
          num.x = fmaf(e.x, l0, num.x); num.y = fmaf(e.y, l1, num.y);
          den.x += e.x;                 den.y += e.y;
        }
        num.x += __shfl_xor(num.x, 32, 64);
        num.y += __shfl_xor(num.y, 32, 64);
        den.x += __shfl_xor(den.x, 32, 64);
        den.y += __shfl_xor(den.y, 32, 64);
        if (rr == 0) {
          float v0 = (cn > 0) ? num.x / den.x : 0.f;
          float v1 = (cn > 0) ? num.y / den.y : 0.f;
          out[((size_t)0 * N_NODES + n) * OUT_DIM + o] = v0;
          out[((size_t)1 * N_NODES + n) * OUT_DIM + o] = v1;
        }
      }
    }
  }
}

extern "C" void kernel_launch(void* const* d_in, const int* in_sizes, int n_in,
                              void* d_out, int out_size, void* d_ws, size_t ws_size,
                              hipStream_t stream) {
  const float* h      = (const float*)d_in[0];
  const float* weight = (const float*)d_in[1];
  const int*   src    = (const int*)d_in[2];
  const int*   dst    = (const int*)d_in[3];
  const float* Wfc    = (const float*)d_in[4];
  const float* bfc    = (const float*)d_in[5];
  const float* Watt   = (const float*)d_in[6];
  const float* batt   = (const float*)d_in[7];
  float* out = (float*)d_out;

  // workspace (~14.4 MB)
  float4*       a_tab   = (float4*)d_ws;                                  // 800 KB
  unsigned int* payload = (unsigned int*)(a_tab + N_NODES);               // 6.4 MB
  __half2*      ezh2    = (__half2*)(payload + (size_t)NBINS * BIN_SLOTS);// 6.4 MB
  int*          cursor  = (int*)(ezh2 + (size_t)N_NODES * OUT_DIM);       // 800 KB (padded)

  // Cooperative grid: co-resident capacity from the occupancy query.
  static int grid_blocks = 0;
  if (grid_blocks == 0) {
    int mb = 0;
    if (hipOccupancyMaxActiveBlocksPerMultiprocessor(&mb, gat_mega, 256, 0)
            != hipSuccess || mb < 1)
      mb = 4;                                   // safe fallback (256,4 bound)
    grid_blocks = mb * 256;                     // 256 CUs on MI355X
    if (grid_blocks > 2048) grid_blocks = 2048;
  }

  void* args[] = {(void*)&h,    (void*)&Wfc,  (void*)&bfc,  (void*)&Watt,
                  (void*)&batt, (void*)&src,  (void*)&dst,  (void*)&weight,
                  (void*)&ezh2, (void*)&a_tab,(void*)&cursor,(void*)&payload,
                  (void*)&out};
  (void)hipLaunchCooperativeKernel(gat_mega, dim3(grid_blocks), dim3(256),
                                   args, 0, stream);
}

// Round 6
// 165.578 us; speedup vs baseline: 2.1519x; 1.9530x over previous
//
#include <hip/hip_runtime.h>
#include <hip/hip_fp16.h>

#define N_NODES 50000
#define N_EDGES 800000
#define IN_DIM  64
#define OUT_DIM 32
#define NODES_PER_BIN 32
#define NBINS   1563                 // ceil(50000/32)
#define NCLS    8
#define CLS_CAP 128                  // per (bin,class): mean 64, +8 sigma; chaining backstops
#define BIN_SLOTS (NCLS * CLS_CAP)   // 1024
#define NCURS   (NBINS * NCLS)       // 12504
#define CUR_STRIDE 16                // one cursor per 64B line (R20)
#define EDGES_PER_THREAD 5
#define SCATTER_BLOCKS (N_EDGES / (256 * EDGES_PER_THREAD))  // 625, exact
#define FC_NODES_PER_BLOCK 16
#define FC_BLOCKS (N_NODES / FC_NODES_PER_BLOCK)  // 3125

// physical XCD id (gfx950: HW_REG_XCC_ID = hwreg 20; learn_hip m09)
__device__ __forceinline__ int get_xcc_id() {
  return (int)(__builtin_amdgcn_s_getreg(63508) & 7u);  // 20 | (31<<11)
}

// R23 (= R20 structure + fc W-path rework).  Mega-kernel experiments (R21/22)
// abandoned: 343-371us vs 162.6 for 3 dispatches.
// fc theory (R1, still unrefuted): per wave-k, 64 scalar ds_read_b32 on the
// W column + 16 ds_read_b128 on h ~= 563cy on the single per-CU LDS pipe;
// x16 wave-k x ~12 blk/CU ~= 46us -> K1's 57us pole.  R1/R2 failed because
// the allocator refuses >64 VGPR under __launch_bounds__.  This round:
// (a) W stored TRANSPOSED + BANK-ROTATED in LDS so the W fragment loads are
//     16 conflict-free ds_read_b128 (works even if rematerialized);
// (b) amdgpu_waves_per_eu(2,4) - the direct codegen attr: min 2 -> 256-reg
//     cap, max 4 -> licenses the allocator off its 8-waves/EU target;
// (c) keep-alive pin on the 16 float4 so they stay VGPR-resident.
__global__ __attribute__((amdgpu_waves_per_eu(2, 4))) __launch_bounds__(256)
void fused_fc_scatter_kernel(
    const float* __restrict__ h, const float* __restrict__ Wfc,
    const float* __restrict__ bfc, const float* __restrict__ Watt,
    const int* __restrict__ src, const int* __restrict__ dst,
    const float* __restrict__ weight,
    __half2* __restrict__ ezh2, float4* __restrict__ a_tab,
    int* __restrict__ cursor, unsigned int* __restrict__ payload) {
  __shared__ float Wl[IN_DIM * OUT_DIM];                    // 8 KB (rotated W^T)
  __shared__ float4 hs4[FC_NODES_PER_BLOCK * 2 * 16];       // 8 KB
  int t = threadIdx.x;

  if (blockIdx.x < SCATTER_BLOCKS) {
    int xcc = get_xcc_id();                  // wave-uniform
    int base = blockIdx.x * (256 * EDGES_PER_THREAD);
    int sA[EDGES_PER_THREAD], dA[EDGES_PER_THREAD];
    float wv[EDGES_PER_THREAD];
#pragma unroll
    for (int k = 0; k < EDGES_PER_THREAD; ++k) {
      int e = base + k * 256 + t;            // coalesced per k, exact coverage
      sA[k] = src[e];
      dA[k] = dst[e];
      wv[k] = weight[e];
    }
    unsigned int recA[EDGES_PER_THREAD];
    int binA[EDGES_PER_THREAD];
#pragma unroll
    for (int k = 0; k < EDGES_PER_THREAD; ++k) {
      recA[k] = ((unsigned int)sA[k] << 16) |
                ((unsigned int)(dA[k] & 31) << 11) |
                ((unsigned int)__float2int_rn(wv[k] * 2047.0f) & 2047u);
      binA[k] = dA[k] >> 5;
    }
    int posA[EDGES_PER_THREAD];
#pragma unroll
    for (int k = 0; k < EDGES_PER_THREAD; ++k)   // 5 independent atomics in flight
      posA[k] = atomicAdd(&cursor[(xcc * NBINS + binA[k]) * CUR_STRIDE], 1);
#pragma unroll
    for (int k = 0; k < EDGES_PER_THREAD; ++k) {
      int c = xcc, pos = posA[k];
      if (pos < CLS_CAP) {
        payload[(size_t)binA[k] * BIN_SLOTS + c * CLS_CAP + pos] = recA[k];
      } else {
#pragma unroll 1
        for (int a = 1; a < NCLS; ++a) {     // overflow chain: ~never taken
          c = (c + 1) & 7;
          pos = atomicAdd(&cursor[(c * NBINS + binA[k]) * CUR_STRIDE], 1);
          if (pos < CLS_CAP) {
            payload[(size_t)binA[k] * BIN_SLOTS + c * CLS_CAP + pos] = recA[k];
            break;
          }
        }
      }
    }
    return;
  }

  // ---- fc role: 16 nodes per block ----
  int n0 = (blockIdx.x - SCATTER_BLOCKS) * FC_NODES_PER_BLOCK;
  // Wl layout: row o (32 rows x 64 floats = 256B-aligned rows); logical
  // float4 chunk c of row o stored at physical slot (c+o)&15.  Lane o's
  // b128 read of chunk c -> banks 4*((c+o)&15): distinct for o=0..15,
  // 2-way (free) for o vs o+16, broadcast across the b=0/1 pair.
  for (int idx = t; idx < IN_DIM * OUT_DIM; idx += 256) {
    int i = idx >> 5, o2 = idx & 31;         // Wfc[i][o2], row-major [64][32]
    int c = i >> 2, p = i & 3;
    Wl[o2 * 64 + (((c + o2) & 15) << 2) + p] = Wfc[idx];
  }
#pragma unroll
  for (int f = t; f < FC_NODES_PER_BLOCK * 2 * 16; f += 256) {
    int ns = f >> 5, sb = (f >> 4) & 1, i4 = f & 15;
    hs4[f] = ((const float4*)h)[((size_t)sb * N_NODES + (n0 + ns)) * 16 + i4];
  }
  __syncthreads();
  int w = t >> 6, lane = t & 63, o = lane & 31, b = lane >> 5;
  // 16 conflict-free ds_read_b128 -> W column in 64 VGPRs, pinned.
  const float4* Wrow = (const float4*)(Wl + o * 64);
  float4 w4[16];
#pragma unroll
  for (int c = 0; c < 16; ++c) w4[c] = Wrow[(c + o) & 15];
#pragma unroll
  for (int c = 0; c < 16; ++c)
    asm volatile("" : "+v"(w4[c].x), "+v"(w4[c].y), "+v"(w4[c].z), "+v"(w4[c].w));
  float bo = bfc[o];
  float wo1 = Watt[o], wo2 = Watt[OUT_DIM + o];
#pragma unroll
  for (int k = 0; k < 4; ++k) {
    int ns = w * 4 + k;
    int n = n0 + ns;
    float acc = bo;
#pragma unroll
    for (int i4 = 0; i4 < 16; ++i4) {
      float4 hv = hs4[(ns * 2 + b) * 16 + i4];   // wave-broadcast (2 addrs: free)
      acc = fmaf(hv.x, w4[i4].x, acc);
      acc = fmaf(hv.y, w4[i4].y, acc);
      acc = fmaf(hv.z, w4[i4].z, acc);
      acc = fmaf(hv.w, w4[i4].w, acc);
    }
    float ez = __expf(acc);
    float ezo = __shfl(ez, lane ^ 32, 64);       // partner batch's value
    if (b == 0) {
      __half2 hv2;
      hv2.x = __float2half(ez);
      hv2.y = __float2half(ezo);
      ezh2[(size_t)n * OUT_DIM + o] = hv2;
    }
    float ps = acc * wo1, pd = acc * wo2;
#pragma unroll
    for (int m = 16; m >= 1; m >>= 1) {
      ps += __shfl_xor(ps, m, 64);
      pd += __shfl_xor(pd, m, 64);
    }
    if (o == 0) ((float2*)(a_tab + n))[b] = make_float2(ps, pd);
  }
}

// K2 (R13/R17 measured-best config): 2 blocks per bin; LDS counting sort (int
// atomics), each wave owns 4 nodes; half-wave (rr) record split; half2 ez
// gathers cover both batches per load.  Payload load predicated on the
// per-class fill count.
__global__ __launch_bounds__(256) void accum_kernel(
    const __half2* __restrict__ ezh2, const unsigned int* __restrict__ payload,
    const int* __restrict__ cursor, const float4* __restrict__ a_tab4,
    const float* __restrict__ Watt, const float* __restrict__ batt,
    float* __restrict__ out) {
  __shared__ unsigned int rec[BIN_SLOTS];     // 4 KB
  __shared__ unsigned int sorted[BIN_SLOTS];  // 4 KB
  __shared__ int c8[NCLS];
  __shared__ int hist[NODES_PER_BIN];
  __shared__ int off[NODES_PER_BIN];
  __shared__ int cnt2[NODES_PER_BIN];
  int t = threadIdx.x;
  int bin = blockIdx.x >> 1;
  int half = blockIdx.x & 1;
  if (t < NCLS) {
    int c = cursor[(t * NBINS + bin) * CUR_STRIDE];   // transposed+padded layout
    c8[t] = c > CLS_CAP ? CLS_CAP : (c < 0 ? 0 : c);
  }
  if (t < NODES_PER_BIN) { hist[t] = 0; cnt2[t] = 0; }
  __syncthreads();
  const unsigned int* seg = payload + (size_t)bin * BIN_SLOTS;
  for (int j = t; j < BIN_SLOTS; j += 256) {
    if ((j & (CLS_CAP - 1)) < c8[j >> 7]) {   // only fetch filled slots
      unsigned int r = seg[j];
      rec[j] = r;
      atomicAdd(&hist[(r >> 11) & 31], 1);
    }
  }
  __syncthreads();
  if (t < 64) {  // exclusive shuffle scan of 32 counts (wave 0)
    int v = (t < 32) ? hist[t] : 0;
    int orig = v;
#pragma unroll
    for (int d1 = 1; d1 < 32; d1 <<= 1) {
      int x = __shfl_up(v, d1, 64);
      if (t >= d1) v += x;
    }
    if (t < 32) off[t] = v - orig;
  }
  __syncthreads();
  for (int j = t; j < BIN_SLOTS; j += 256) {
    if ((j & (CLS_CAP - 1)) < c8[j >> 7]) {
      unsigned int r = rec[j];
      int nl = (r >> 11) & 31;
      sorted[off[nl] + atomicAdd(&cnt2[nl], 1)] = r;   // total <= 1024: in bounds
    }
  }
  __syncthreads();

  int w = t >> 6, lane = t & 63, o = lane & 31, rr = lane >> 5;
  float wA = Watt[2 * OUT_DIM];
  float bA = batt[0];
  const float kInvQ = 1.0f / 2047.0f;
#pragma unroll
  for (int k = 0; k < 4; ++k) {
    int nl = half * 16 + w * 4 + k;             // wave-uniform
    int n = bin * NODES_PER_BIN + nl;
    if (n >= N_NODES) break;
    int cn = hist[nl];
    int base = off[nl];
    float4 an = a_tab4[n];
    float adx = an.y, ady = an.w;               // a_d(n,b0), a_d(n,b1)
    float2 num = make_float2(0.f, 0.f), den = make_float2(0.f, 0.f);
    int i = 0;
    for (; i + 3 < cn; i += 4) {                // 2 records per half-wave iter
      unsigned int rA = sorted[base + i + rr];
      unsigned int rB = sorted[base + i + 2 + rr];
      int sA = rA >> 16, sB = rB >> 16;
      __half2 eA2 = ezh2[(size_t)sA * OUT_DIM + o];
      __half2 eB2 = ezh2[(size_t)sB * OUT_DIM + o];
      float4 aA = a_tab4[sA];
      float4 aB = a_tab4[sB];
      float wtA = fmaf((rA & 2047u) * kInvQ, wA, bA);
      float wtB = fmaf((rB & 2047u) * kInvQ, wA, bA);
      float l0A = aA.x + adx + wtA, l1A = aA.z + ady + wtA;
      float l0B = aB.x + adx + wtB, l1B = aB.z + ady + wtB;
      l0A = l0A > 0.f ? l0A : 0.01f * l0A;
      l1A = l1A > 0.f ? l1A : 0.01f * l1A;
      l0B = l0B > 0.f ? l0B : 0.01f * l0B;
      l1B = l1B > 0.f ? l1B : 0.01f * l1B;
      float2 eA = __half22float2(eA2);
      float2 eB = __half22float2(eB2);
      num.x = fmaf(eA.x, l0A, num.x); num.y = fmaf(eA.y, l1A, num.y);
      den.x += eA.x;                  den.y += eA.y;
      num.x = fmaf(eB.x, l0B, num.x); num.y = fmaf(eB.y, l1B, num.y);
      den.x += eB.x;                  den.y += eB.y;
    }
    for (; i < cn; i += 2) {                    // guarded tail
      int idx = i + rr;
      float m = (idx < cn) ? 1.f : 0.f;
      int idxc = (idx < cn) ? idx : cn - 1;
      unsigned int r = sorted[base + idxc];
      int s = r >> 16;
      __half2 e2 = ezh2[(size_t)s * OUT_DIM + o];
      float4 as4 = a_tab4[s];
      float wt = fmaf((r & 2047u) * kInvQ, wA, bA);
      float l0 = as4.x + adx + wt, l1 = as4.z + ady + wt;
      l0 = l0 > 0.f ? l0 : 0.01f * l0;
      l1 = l1 > 0.f ? l1 : 0.01f * l1;
      float2 e = __half22float2(e2);
      e.x *= m; e.y *= m;
      num.x = fmaf(e.x, l0, num.x); num.y = fmaf(e.y, l1, num.y);
      den.x += e.x;                 den.y += e.y;
    }
    num.x += __shfl_xor(num.x, 32, 64);
    num.y += __shfl_xor(num.y, 32, 64);
    den.x += __shfl_xor(den.x, 32, 64);
    den.y += __shfl_xor(den.y, 32, 64);
    if (rr == 0) {
      float v0 = (cn > 0) ? num.x / den.x : 0.f;
      float v1 = (cn > 0) ? num.y / den.y : 0.f;
      out[((size_t)0 * N_NODES + n) * OUT_DIM + o] = v0;
      out[((size_t)1 * N_NODES + n) * OUT_DIM + o] = v1;
    }
  }
}

extern "C" void kernel_launch(void* const* d_in, const int* in_sizes, int n_in,
                              void* d_out, int out_size, void* d_ws, size_t ws_size,
                              hipStream_t stream) {
  const float* h      = (const float*)d_in[0];
  const float* weight = (const float*)d_in[1];
  const int*   src    = (const int*)d_in[2];
  const int*   dst    = (const int*)d_in[3];
  const float* Wfc    = (const float*)d_in[4];
  const float* bfc    = (const float*)d_in[5];
  const float* Watt   = (const float*)d_in[6];
  const float* batt   = (const float*)d_in[7];
  float* out = (float*)d_out;

  // workspace (~14.4 MB)
  float4*       a_tab   = (float4*)d_ws;                                  // 800 KB
  unsigned int* payload = (unsigned int*)(a_tab + N_NODES);               // 6.4 MB
  __half2*      ezh2    = (__half2*)(payload + (size_t)NBINS * BIN_SLOTS);// 6.4 MB
  int*          cursor  = (int*)(ezh2 + (size_t)N_NODES * OUT_DIM);       // 800 KB (padded)

  (void)hipMemsetAsync(cursor, 0, NCURS * CUR_STRIDE * sizeof(int), stream);
  fused_fc_scatter_kernel<<<SCATTER_BLOCKS + FC_BLOCKS, 256, 0, stream>>>(
      h, Wfc, bfc, Watt, src, dst, weight, ezh2, a_tab, cursor, payload);
  accum_kernel<<<NBINS * 2, 256, 0, stream>>>(ezh2, payload, cursor, a_tab,
                                              Watt, batt, out);
}